// Round 1
// baseline (8321.647 us; speedup 1.0000x reference)
//
#include <hip/hip_runtime.h>
#include <math.h>

static __device__ __forceinline__ float sigf(float x){
  return 1.0f / (1.0f + __expf(-x));
}
static __device__ __forceinline__ float tanhf_fast(float x){
  float ax = fabsf(x);
  float e  = __expf(-2.0f * ax);
  float t  = (1.0f - e) / (1.0f + e);
  return copysignf(t, x);
}

#define GATE(comp) { \
  const float rr = sigf(sr.comp); \
  const float zz = sigf(sz.comp); \
  const float nn = tanhf_fast(fmaf(rr, gh.comp, gi.comp)); \
  hn.comp = nn + zz * (ho.comp - nn); }

// ---------------------------------------------------------------------------
// L1: I=1, H=100, dilation 1, 512 steps, chains == batch (1024).
// grid 512: blocks 0..255 forward, 256..511 backward. 320 threads.
// Each block owns 4 chains. Thread t<300 owns row t of whh (100 VGPR weights).
// h kept transposed in LDS hT[j][chain]; inner loop = broadcast ds_read_b128
// + 4 fmaf. Stores h at s%4==3 into ws (only positions L2 needs) and final h
// (s=511) into out columns [0,100) fwd / [200,300) bwd.
// ---------------------------------------------------------------------------
__global__ __launch_bounds__(320, 3)
void gru_l1(const float* __restrict__ data,
            const float* __restrict__ wih_f, const float* __restrict__ whh_f,
            const float* __restrict__ bih_f, const float* __restrict__ bhh_f,
            const float* __restrict__ wih_b, const float* __restrict__ whh_b,
            const float* __restrict__ bih_b, const float* __restrict__ bhh_b,
            float* __restrict__ x1f, float* __restrict__ x1b,
            float* __restrict__ out)
{
  const int dir = (int)(blockIdx.x >> 8);
  const int blk = (int)(blockIdx.x & 255);
  const int t   = (int)threadIdx.x;
  const float* __restrict__ wih = dir ? wih_b : wih_f;
  const float* __restrict__ whh = dir ? whh_b : whh_f;
  const float* __restrict__ bih = dir ? bih_b : bih_f;
  const float* __restrict__ bhh = dir ? bhh_b : bhh_f;
  float* __restrict__ x1 = dir ? x1b : x1f;
  const int obase = dir ? 200 : 0;
  const int b0 = blk * 4;

  __shared__ __align__(16) float xs[4][512];
  __shared__ __align__(16) float hT[100][4];
  __shared__ __align__(16) float Sb[200][4];
  __shared__ __align__(16) float Gni[100][4];
  __shared__ __align__(16) float Gnh[100][4];

  // stage the entire (reversed if bwd) scalar input sequence for 4 chains
  for (int k = t; k < 2048; k += 320){
    const int cc = k >> 9;
    const int s  = k & 511;
    xs[cc][s] = data[(size_t)(b0 + cc) * 512 + (size_t)(dir ? (511 - s) : s)];
  }
  if (t < 100){
    hT[t][0] = 0.f; hT[t][1] = 0.f; hT[t][2] = 0.f; hT[t][3] = 0.f;
  }

  float w[100];
  float bi = 0.f, bh = 0.f, wx = 0.f;
  if (t < 300){
    #pragma unroll
    for (int q = 0; q < 25; ++q){
      const float4 v = *(const float4*)(whh + (size_t)t * 100 + q * 4);
      w[q*4+0] = v.x; w[q*4+1] = v.y; w[q*4+2] = v.z; w[q*4+3] = v.w;
    }
    bi = bih[t]; bh = bhh[t]; wx = wih[t];
  }
  __syncthreads();

  #pragma unroll 1
  for (int s = 0; s < 512; ++s){
    if (t < 300){
      float a0 = bh, a1 = bh, a2 = bh, a3 = bh;
      #pragma unroll
      for (int j = 0; j < 100; ++j){
        const float4 h4 = *(const float4*)(&hT[j][0]);   // wave-broadcast read
        a0 = fmaf(w[j], h4.x, a0);
        a1 = fmaf(w[j], h4.y, a1);
        a2 = fmaf(w[j], h4.z, a2);
        a3 = fmaf(w[j], h4.w, a3);
      }
      const float g0 = fmaf(wx, xs[0][s], bi);
      const float g1 = fmaf(wx, xs[1][s], bi);
      const float g2 = fmaf(wx, xs[2][s], bi);
      const float g3 = fmaf(wx, xs[3][s], bi);
      if (t < 200){
        *(float4*)(&Sb[t][0]) = make_float4(g0+a0, g1+a1, g2+a2, g3+a3);
      } else {
        *(float4*)(&Gni[t-200][0]) = make_float4(g0, g1, g2, g3);
        *(float4*)(&Gnh[t-200][0]) = make_float4(a0, a1, a2, a3);
      }
    }
    __syncthreads();
    if (t < 100){
      const float4 sr = *(const float4*)(&Sb[t][0]);
      const float4 sz = *(const float4*)(&Sb[100+t][0]);
      const float4 gi = *(const float4*)(&Gni[t][0]);
      const float4 gh = *(const float4*)(&Gnh[t][0]);
      const float4 ho = *(const float4*)(&hT[t][0]);
      float4 hn;
      GATE(x) GATE(y) GATE(z) GATE(w)
      *(float4*)(&hT[t][0]) = hn;
      if ((s & 3) == 3){
        const int cs = s >> 2;
        x1[((size_t)(b0+0)*128 + cs)*100 + t] = hn.x;
        x1[((size_t)(b0+1)*128 + cs)*100 + t] = hn.y;
        x1[((size_t)(b0+2)*128 + cs)*100 + t] = hn.z;
        x1[((size_t)(b0+3)*128 + cs)*100 + t] = hn.w;
      }
      if (s == 511){
        out[(size_t)(b0+0)*400 + obase + t] = hn.x;
        out[(size_t)(b0+1)*400 + obase + t] = hn.y;
        out[(size_t)(b0+2)*400 + obase + t] = hn.z;
        out[(size_t)(b0+3)*400 + obase + t] = hn.w;
      }
    }
    __syncthreads();
  }
}

// ---------------------------------------------------------------------------
// L2: I=100, H=50, only lane-3 chains (1 per batch elem), 128 steps.
// grid 512 (2 dirs x 256), 192 threads, 4 chains/block. Thread t<150 owns
// row t: wih row (100 VGPRs) + whh row (50 VGPRs). x staged per step.
// Stores h at c%4==3 to ws (what L3 needs) and final h (c=127) to out
// columns [100,150) fwd / [300,350) bwd.
// ---------------------------------------------------------------------------
__global__ __launch_bounds__(192, 2)
void gru_l2(const float* __restrict__ x1f, const float* __restrict__ x1b,
            const float* __restrict__ wih_f, const float* __restrict__ whh_f,
            const float* __restrict__ bih_f, const float* __restrict__ bhh_f,
            const float* __restrict__ wih_b, const float* __restrict__ whh_b,
            const float* __restrict__ bih_b, const float* __restrict__ bhh_b,
            float* __restrict__ x2f, float* __restrict__ x2b,
            float* __restrict__ out)
{
  const int dir = (int)(blockIdx.x >> 8);
  const int blk = (int)(blockIdx.x & 255);
  const int t   = (int)threadIdx.x;
  const float* __restrict__ wih = dir ? wih_b : wih_f;
  const float* __restrict__ whh = dir ? whh_b : whh_f;
  const float* __restrict__ bih = dir ? bih_b : bih_f;
  const float* __restrict__ bhh = dir ? bhh_b : bhh_f;
  const float* __restrict__ x1 = dir ? x1b : x1f;
  float* __restrict__ x2 = dir ? x2b : x2f;
  const int obase = dir ? 300 : 100;
  const int b0 = blk * 4;

  __shared__ __align__(16) float hT[50][4];
  __shared__ __align__(16) float xT[100][4];
  __shared__ __align__(16) float Sb[100][4];
  __shared__ __align__(16) float Gni[50][4];
  __shared__ __align__(16) float Gnh[50][4];

  float wi[100], wh[50];
  float bi = 0.f, bh = 0.f;
  if (t < 150){
    #pragma unroll
    for (int q = 0; q < 25; ++q){
      const float4 v = *(const float4*)(wih + (size_t)t * 100 + q * 4);
      wi[q*4+0] = v.x; wi[q*4+1] = v.y; wi[q*4+2] = v.z; wi[q*4+3] = v.w;
    }
    #pragma unroll
    for (int q = 0; q < 25; ++q){
      const float2 v = *(const float2*)(whh + (size_t)t * 50 + q * 2);
      wh[q*2+0] = v.x; wh[q*2+1] = v.y;
    }
    bi = bih[t]; bh = bhh[t];
  }
  if (t < 50){ hT[t][0]=0.f; hT[t][1]=0.f; hT[t][2]=0.f; hT[t][3]=0.f; }
  // stage x for step 0
  for (int k = t; k < 400; k += 192){
    const int cc = k / 100, j = k - cc * 100;
    xT[j][cc] = x1[((size_t)(b0+cc)*128 + 0)*100 + j];
  }
  __syncthreads();

  #pragma unroll 1
  for (int s = 0; s < 128; ++s){
    if (t < 150){
      float ah0 = bh, ah1 = bh, ah2 = bh, ah3 = bh;
      #pragma unroll
      for (int j = 0; j < 50; ++j){
        const float4 h4 = *(const float4*)(&hT[j][0]);
        ah0 = fmaf(wh[j], h4.x, ah0);
        ah1 = fmaf(wh[j], h4.y, ah1);
        ah2 = fmaf(wh[j], h4.z, ah2);
        ah3 = fmaf(wh[j], h4.w, ah3);
      }
      float ai0 = bi, ai1 = bi, ai2 = bi, ai3 = bi;
      #pragma unroll
      for (int j = 0; j < 100; ++j){
        const float4 x4 = *(const float4*)(&xT[j][0]);
        ai0 = fmaf(wi[j], x4.x, ai0);
        ai1 = fmaf(wi[j], x4.y, ai1);
        ai2 = fmaf(wi[j], x4.z, ai2);
        ai3 = fmaf(wi[j], x4.w, ai3);
      }
      if (t < 100){
        *(float4*)(&Sb[t][0]) = make_float4(ai0+ah0, ai1+ah1, ai2+ah2, ai3+ah3);
      } else {
        *(float4*)(&Gni[t-100][0]) = make_float4(ai0, ai1, ai2, ai3);
        *(float4*)(&Gnh[t-100][0]) = make_float4(ah0, ah1, ah2, ah3);
      }
    }
    __syncthreads();
    if (t < 50){
      const float4 sr = *(const float4*)(&Sb[t][0]);
      const float4 sz = *(const float4*)(&Sb[50+t][0]);
      const float4 gi = *(const float4*)(&Gni[t][0]);
      const float4 gh = *(const float4*)(&Gnh[t][0]);
      const float4 ho = *(const float4*)(&hT[t][0]);
      float4 hn;
      GATE(x) GATE(y) GATE(z) GATE(w)
      *(float4*)(&hT[t][0]) = hn;
      if ((s & 3) == 3){
        const int k2 = s >> 2;
        x2[((size_t)(b0+0)*32 + k2)*50 + t] = hn.x;
        x2[((size_t)(b0+1)*32 + k2)*50 + t] = hn.y;
        x2[((size_t)(b0+2)*32 + k2)*50 + t] = hn.z;
        x2[((size_t)(b0+3)*32 + k2)*50 + t] = hn.w;
      }
      if (s == 127){
        out[(size_t)(b0+0)*400 + obase + t] = hn.x;
        out[(size_t)(b0+1)*400 + obase + t] = hn.y;
        out[(size_t)(b0+2)*400 + obase + t] = hn.z;
        out[(size_t)(b0+3)*400 + obase + t] = hn.w;
      }
    } else if (s + 1 < 128){
      for (int k = t - 50; k < 400; k += 142){
        const int cc = k / 100, j = k - cc * 100;
        xT[j][cc] = x1[((size_t)(b0+cc)*128 + (s+1))*100 + j];
      }
    }
    __syncthreads();
  }
}

// ---------------------------------------------------------------------------
// L3: I=50, H=50, only lane-15 chains (1 per batch elem), 32 steps.
// Final h (k=31) -> out columns [150,200) fwd / [350,400) bwd.
// ---------------------------------------------------------------------------
__global__ __launch_bounds__(192, 2)
void gru_l3(const float* __restrict__ x2f, const float* __restrict__ x2b,
            const float* __restrict__ wih_f, const float* __restrict__ whh_f,
            const float* __restrict__ bih_f, const float* __restrict__ bhh_f,
            const float* __restrict__ wih_b, const float* __restrict__ whh_b,
            const float* __restrict__ bih_b, const float* __restrict__ bhh_b,
            float* __restrict__ out)
{
  const int dir = (int)(blockIdx.x >> 8);
  const int blk = (int)(blockIdx.x & 255);
  const int t   = (int)threadIdx.x;
  const float* __restrict__ wih = dir ? wih_b : wih_f;
  const float* __restrict__ whh = dir ? whh_b : whh_f;
  const float* __restrict__ bih = dir ? bih_b : bih_f;
  const float* __restrict__ bhh = dir ? bhh_b : bhh_f;
  const float* __restrict__ x2 = dir ? x2b : x2f;
  const int obase = dir ? 350 : 150;
  const int b0 = blk * 4;

  __shared__ __align__(16) float hT[50][4];
  __shared__ __align__(16) float xT[50][4];
  __shared__ __align__(16) float Sb[100][4];
  __shared__ __align__(16) float Gni[50][4];
  __shared__ __align__(16) float Gnh[50][4];

  float wi[50], wh[50];
  float bi = 0.f, bh = 0.f;
  if (t < 150){
    #pragma unroll
    for (int q = 0; q < 25; ++q){
      const float2 v = *(const float2*)(wih + (size_t)t * 50 + q * 2);
      wi[q*2+0] = v.x; wi[q*2+1] = v.y;
    }
    #pragma unroll
    for (int q = 0; q < 25; ++q){
      const float2 v = *(const float2*)(whh + (size_t)t * 50 + q * 2);
      wh[q*2+0] = v.x; wh[q*2+1] = v.y;
    }
    bi = bih[t]; bh = bhh[t];
  }
  if (t < 50){ hT[t][0]=0.f; hT[t][1]=0.f; hT[t][2]=0.f; hT[t][3]=0.f; }
  for (int k = t; k < 200; k += 192){
    const int cc = k / 50, j = k - cc * 50;
    xT[j][cc] = x2[((size_t)(b0+cc)*32 + 0)*50 + j];
  }
  __syncthreads();

  #pragma unroll 1
  for (int s = 0; s < 32; ++s){
    if (t < 150){
      float ah0 = bh, ah1 = bh, ah2 = bh, ah3 = bh;
      float ai0 = bi, ai1 = bi, ai2 = bi, ai3 = bi;
      #pragma unroll
      for (int j = 0; j < 50; ++j){
        const float4 h4 = *(const float4*)(&hT[j][0]);
        ah0 = fmaf(wh[j], h4.x, ah0);
        ah1 = fmaf(wh[j], h4.y, ah1);
        ah2 = fmaf(wh[j], h4.z, ah2);
        ah3 = fmaf(wh[j], h4.w, ah3);
      }
      #pragma unroll
      for (int j = 0; j < 50; ++j){
        const float4 x4 = *(const float4*)(&xT[j][0]);
        ai0 = fmaf(wi[j], x4.x, ai0);
        ai1 = fmaf(wi[j], x4.y, ai1);
        ai2 = fmaf(wi[j], x4.z, ai2);
        ai3 = fmaf(wi[j], x4.w, ai3);
      }
      if (t < 100){
        *(float4*)(&Sb[t][0]) = make_float4(ai0+ah0, ai1+ah1, ai2+ah2, ai3+ah3);
      } else {
        *(float4*)(&Gni[t-100][0]) = make_float4(ai0, ai1, ai2, ai3);
        *(float4*)(&Gnh[t-100][0]) = make_float4(ah0, ah1, ah2, ah3);
      }
    }
    __syncthreads();
    if (t < 50){
      const float4 sr = *(const float4*)(&Sb[t][0]);
      const float4 sz = *(const float4*)(&Sb[50+t][0]);
      const float4 gi = *(const float4*)(&Gni[t][0]);
      const float4 gh = *(const float4*)(&Gnh[t][0]);
      const float4 ho = *(const float4*)(&hT[t][0]);
      float4 hn;
      GATE(x) GATE(y) GATE(z) GATE(w)
      *(float4*)(&hT[t][0]) = hn;
      if (s == 31){
        out[(size_t)(b0+0)*400 + obase + t] = hn.x;
        out[(size_t)(b0+1)*400 + obase + t] = hn.y;
        out[(size_t)(b0+2)*400 + obase + t] = hn.z;
        out[(size_t)(b0+3)*400 + obase + t] = hn.w;
      }
    } else if (s + 1 < 32){
      for (int k = t - 50; k < 200; k += 142){
        const int cc = k / 50, j = k - cc * 50;
        xT[j][cc] = x2[((size_t)(b0+cc)*32 + (s+1))*50 + j];
      }
    }
    __syncthreads();
  }
}

extern "C" void kernel_launch(void* const* d_in, const int* in_sizes, int n_in,
                              void* d_out, int out_size, void* d_ws, size_t ws_size,
                              hipStream_t stream)
{
  const float* data   = (const float*)d_in[0];
  const float* f1_wih = (const float*)d_in[1];
  const float* f1_whh = (const float*)d_in[2];
  const float* f1_bih = (const float*)d_in[3];
  const float* f1_bhh = (const float*)d_in[4];
  const float* f2_wih = (const float*)d_in[5];
  const float* f2_whh = (const float*)d_in[6];
  const float* f2_bih = (const float*)d_in[7];
  const float* f2_bhh = (const float*)d_in[8];
  const float* f3_wih = (const float*)d_in[9];
  const float* f3_whh = (const float*)d_in[10];
  const float* f3_bih = (const float*)d_in[11];
  const float* f3_bhh = (const float*)d_in[12];
  const float* b1_wih = (const float*)d_in[13];
  const float* b1_whh = (const float*)d_in[14];
  const float* b1_bih = (const float*)d_in[15];
  const float* b1_bhh = (const float*)d_in[16];
  const float* b2_wih = (const float*)d_in[17];
  const float* b2_whh = (const float*)d_in[18];
  const float* b2_bih = (const float*)d_in[19];
  const float* b2_bhh = (const float*)d_in[20];
  const float* b3_wih = (const float*)d_in[21];
  const float* b3_whh = (const float*)d_in[22];
  const float* b3_bih = (const float*)d_in[23];
  const float* b3_bhh = (const float*)d_in[24];
  float* out = (float*)d_out;

  const size_t X1N = (size_t)1024 * 128 * 100;  // L1 stored outputs (s%4==3)
  const size_t X2N = (size_t)1024 * 32 * 50;    // L2 stored outputs (c%4==3)
  if (ws_size < (2 * X1N + 2 * X2N) * sizeof(float)) return;  // visible failure
  float* wsf = (float*)d_ws;
  float* x1f = wsf;
  float* x1b = wsf + X1N;
  float* x2f = wsf + 2 * X1N;
  float* x2b = wsf + 2 * X1N + X2N;

  gru_l1<<<dim3(512), dim3(320), 0, stream>>>(
      data, f1_wih, f1_whh, f1_bih, f1_bhh,
      b1_wih, b1_whh, b1_bih, b1_bhh, x1f, x1b, out);
  gru_l2<<<dim3(512), dim3(192), 0, stream>>>(
      x1f, x1b, f2_wih, f2_whh, f2_bih, f2_bhh,
      b2_wih, b2_whh, b2_bih, b2_bhh, x2f, x2b, out);
  gru_l3<<<dim3(512), dim3(192), 0, stream>>>(
      x2f, x2b, f3_wih, f3_whh, f3_bih, f3_bhh,
      b3_wih, b3_whh, b3_bih, b3_bhh, out);
}